// Round 11
// baseline (114.053 us; speedup 1.0000x reference)
//
#include <hip/hip_runtime.h>
#include <hip/hip_bf16.h>

// out[b,d,r] = sum_c p[b,c] * softmax_d( x[b,:] @ W[:, c*8+d, r] + bias[c,d,r] )
// B=16384, F=128, C=8, R=64.
//
// R10->R11: R10's 16x16x32 1-mt structure pays 1 KB LDS per 16k-FLOP MFMA
// (1 GB stream, ~20 us floor).  mfma_f32_32x32x16_bf16 gives 32 rows per
// 1 KB fragment (2x FLOP/LDS-byte) at acc=16 regs.  Roles swapped: A = W
// (LDS-staged), B = x (registers) -> C/D rows = W-cols; prepass permutes
// W-cols so d = bits{r0,r1,r3} of the row index => the 8 d-values sit in
// regs jj=0..7 / 8..15 of ONE lane => in-lane softmax, 1 rcp per 8 elems.
// Block = 4 waves (2 b-groups x 2 rg-pairs) = 64 b x 8 d x 16 r -> final
// 32 KB LDS exchange emits full 64-B out lines (1 line/thread x2).
// LDS: 524 MB reads + 268 MB staging (~15 us pipe), regs ~115 < 128.

#define LOG2E 1.44269504088896340736f

typedef __bf16 bf16x8 __attribute__((ext_vector_type(8)));
typedef float  f32x4  __attribute__((ext_vector_type(4)));
typedef float  f32x16 __attribute__((ext_vector_type(16)));

#define AS1(p) ((const __attribute__((address_space(1))) unsigned int*)(p))
#define AS3(p) ((__attribute__((address_space(3))) unsigned int*)(p))

// Row mapping (C/D row rho = (reg&3) + 8*(reg>>2) + 4*(lane>>5), m74/m101):
//   d  = rho0 + 2*rho1 + 4*rho3  = jj&7          (jj = reg)
//   rr = rho2 + 2*rho4           = half + 2*(jj>>3)
// W column for fragment (c, rg, row rho): n = (c*8+d)*64 + rg*4 + rr.

// ---------------------------------------------------------------------------
// Prepass 1: W fp32 (128 x 4096) -> bf16 A-fragments for 32x32x16.
// Fragment g = [c][rg][kq] (1 KB): lane holds A[m=lane&31][k=kq*16+(lane>>5)*8+j].
// ---------------------------------------------------------------------------
__global__ void wconv_kernel(const float* __restrict__ W, __bf16* __restrict__ wf) {
    int f    = blockIdx.x * 256 + threadIdx.x;   // 0..65535
    int lane = f & 63;
    int g    = f >> 6;
    int kq   = g & 7;
    int rg   = (g >> 3) & 15;
    int c    = g >> 7;
    int rho  = lane & 31;
    int kh   = lane >> 5;
    int d    = (rho & 3) | ((rho >> 1) & 4);          // bits 0,1,3 of rho
    int rr   = ((rho >> 2) & 1) | ((rho >> 3) & 2);   // bits 2,4 of rho
    int n    = (c * 8 + d) * 64 + rg * 4 + rr;
    int kbase = kq * 16 + kh * 8;
    bf16x8 frag;
    for (int j = 0; j < 8; ++j)
        frag[j] = (__bf16)W[(kbase + j) * 4096 + n];
    *(bf16x8*)(wf + f * 8) = frag;
}

// ---------------------------------------------------------------------------
// Prepass 2: bias -> [rg][c][h][jj] order, pre-scaled by log2(e).  16 KB.
// ---------------------------------------------------------------------------
__global__ void bconv_kernel(const float* __restrict__ bias, float* __restrict__ bs) {
    int t  = blockIdx.x * 256 + threadIdx.x;     // 0..4095
    int jj = t & 15;
    int h  = (t >> 4) & 1;
    int c  = (t >> 5) & 7;
    int rg = t >> 8;
    int d  = jj & 7;
    int r  = rg * 4 + h + 2 * (jj >> 3);
    bs[t] = bias[(c * 8 + d) * 64 + r] * LOG2E;
}

// ---------------------------------------------------------------------------
// Fused kernel.  Block: 256 thr (4 waves), 64 b x 8 d x 16 r (rp = blk&3).
// Wave ww: b-group = ww&1 (32 b), rg-pair = ww>>1 (tiles rg' = 2*(ww>>1)+tt).
// Per c: stage 32 frag-KB (wave ww stages rg'=ww), 2 tiles x 8 MFMA each.
// ---------------------------------------------------------------------------
__global__ __launch_bounds__(256, 4)
void fused_kernel(const float* __restrict__ x, const float* __restrict__ p,
                  const float* __restrict__ bs, const __bf16* __restrict__ wf,
                  float* __restrict__ out) {
    __shared__ __align__(16) char lds[32768];

    const int lane = threadIdx.x & 63;
    const int ww   = threadIdx.x >> 6;
    const int l31  = lane & 31;
    const int h    = lane >> 5;
    const int rp   = blockIdx.x & 3;             // 16-r chunk
    const int b0   = (blockIdx.x >> 2) * 64;
    const int bw   = b0 + (ww & 1) * 32;         // wave's 32-b base
    const int rgp  = ww >> 1;                    // wave's rg-pair (local)

    // x as B-operand: bfr[kq][j] = x_bf16[bw + l31][kq*16 + h*8 + j]
    bf16x8 bfr[8];
    {
        const float* xr = x + (bw + l31) * 128 + h * 8;
#pragma unroll
        for (int kq = 0; kq < 8; ++kq) {
            float4 lo = *(const float4*)(xr + kq * 16);
            float4 hi = *(const float4*)(xr + kq * 16 + 4);
            bf16x8 fr;
            fr[0] = (__bf16)lo.x; fr[1] = (__bf16)lo.y;
            fr[2] = (__bf16)lo.z; fr[3] = (__bf16)lo.w;
            fr[4] = (__bf16)hi.x; fr[5] = (__bf16)hi.y;
            fr[6] = (__bf16)hi.z; fr[7] = (__bf16)hi.w;
            bfr[kq] = fr;
        }
    }

    float O0[16], O1[16];
#pragma unroll
    for (int z = 0; z < 16; ++z) { O0[z] = 0.f; O1[z] = 0.f; }

#pragma unroll 1
    for (int c = 0; c < 8; ++c) {
        // stage: wave ww stages local rg' = ww (8 frags x 1 KB)
        {
            const __bf16* g = wf + (size_t)((c * 16 + rp * 4 + ww) * 8) * 512 + lane * 8;
#pragma unroll
            for (int kq = 0; kq < 8; ++kq)
                __builtin_amdgcn_global_load_lds(AS1(g + kq * 512),
                                                 AS3(lds + (ww * 8 + kq) * 1024), 16, 0, 0);
        }
        __syncthreads();

        float pv = p[(bw + l31) * 8 + c];

#pragma unroll
        for (int tt = 0; tt < 2; ++tt) {
            const int rgl = rgp * 2 + tt;        // local rg' in [0,4)
            f32x16 acc;
#pragma unroll
            for (int z = 0; z < 16; ++z) acc[z] = 0.f;
#pragma unroll
            for (int kq = 0; kq < 8; ++kq) {
                bf16x8 a = *(const bf16x8*)(lds + (rgl * 8 + kq) * 1024 + lane * 16);
                acc = __builtin_amdgcn_mfma_f32_32x32x16_bf16(a, bfr[kq], acc, 0, 0, 0);
            }
            const float* bb = bs + (rp * 4 + rgl) * 256 + c * 32 + h * 16;
            float4 bv0 = *(const float4*)(bb);
            float4 bv1 = *(const float4*)(bb + 4);
            float4 bv2 = *(const float4*)(bb + 8);
            float4 bv3 = *(const float4*)(bb + 12);
            float bv[16] = {bv0.x, bv0.y, bv0.z, bv0.w, bv1.x, bv1.y, bv1.z, bv1.w,
                            bv2.x, bv2.y, bv2.z, bv2.w, bv3.x, bv3.y, bv3.z, bv3.w};
            float* O = tt ? O1 : O0;
#pragma unroll
            for (int r3 = 0; r3 < 2; ++r3) {
                float e[8];
#pragma unroll
                for (int dc = 0; dc < 8; ++dc)
                    e[dc] = __builtin_amdgcn_exp2f(
                        __builtin_fmaf(acc[r3 * 8 + dc], LOG2E, bv[r3 * 8 + dc]));
                float s = ((e[0] + e[1]) + (e[2] + e[3])) + ((e[4] + e[5]) + (e[6] + e[7]));
                float scale = pv * __builtin_amdgcn_rcpf(s);
#pragma unroll
                for (int dc = 0; dc < 8; ++dc)
                    O[r3 * 8 + dc] = __builtin_fmaf(e[dc], scale, O[r3 * 8 + dc]);
            }
        }
        __syncthreads();   // protect frags before next c's staging / final dump
    }

    // ---- exchange via LDS -> full 64-B line stores -------------------------
    // dump layout [d][rl][bl]: idx = (d*16+rl)*64 + bl  (bank = bl%32: 2-way, free)
    float* ldsF = (float*)lds;
#pragma unroll
    for (int tt = 0; tt < 2; ++tt) {
        const float* O = tt ? O1 : O0;
        const int rbase = (rgp * 2 + tt) * 4 + h;
        const int bl = (ww & 1) * 32 + l31;
#pragma unroll
        for (int jj = 0; jj < 16; ++jj) {
            int d  = jj & 7;
            int rl = rbase + 2 * (jj >> 3);
            ldsF[(d * 16 + rl) * 64 + bl] = O[jj];
        }
    }
    __syncthreads();
    // 512 lines (64 b x 8 d), thread q -> lines q, q+256
    const int q = threadIdx.x;
#pragma unroll
    for (int li = 0; li < 2; ++li) {
        int ln = q + li * 256;
        int bl = ln & 63;
        int d  = ln >> 6;
        float v[16];
#pragma unroll
        for (int k = 0; k < 16; ++k)
            v[k] = ldsF[(d * 16 + k) * 64 + bl];
        float* dst = out + (size_t)(b0 + bl) * 512 + d * 64 + rp * 16;
#pragma unroll
        for (int ch = 0; ch < 4; ++ch) {
            f32x4 vv = {v[ch * 4], v[ch * 4 + 1], v[ch * 4 + 2], v[ch * 4 + 3]};
            *(f32x4*)(dst + ch * 4) = vv;
        }
    }
}

extern "C" void kernel_launch(void* const* d_in, const int* in_sizes, int n_in,
                              void* d_out, int out_size, void* d_ws, size_t ws_size,
                              hipStream_t stream) {
    const float* x    = (const float*)d_in[0];   // (16384, 128)
    const float* p    = (const float*)d_in[1];   // (16384, 8)
    const float* W    = (const float*)d_in[2];   // (128, 64, 64)
    const float* bias = (const float*)d_in[3];   // (8, 8, 64)
    float* out = (float*)d_out;                  // (16384, 8, 64)
    __bf16* wf = (__bf16*)d_ws;                          // 1 MB A-fragments
    float*  bs = (float*)((char*)d_ws + (1 << 20));      // 16 KB swizzled bias

    wconv_kernel<<<dim3(256), dim3(256), 0, stream>>>(W, wf);
    bconv_kernel<<<dim3(16), dim3(256), 0, stream>>>(bias, bs);
    fused_kernel<<<dim3(1024), dim3(256), 0, stream>>>(x, p, bs, wf, out);
}